// Round 8
// baseline (14280.840 us; speedup 1.0000x reference)
//
#include <hip/hip_runtime.h>
#include <hip/hip_fp16.h>

#define LOG2E 1.44269504088896340736f
#define BB 256
#define TT 128
#define SS 128
#define UU 256

// ---------------- packing helpers ----------------
__device__ __forceinline__ __half2 u2h(unsigned u) {
    union { unsigned x; __half2 h; } c; c.x = u; return c.h;
}
__device__ __forceinline__ unsigned h2u(__half2 h) {
    union { __half2 h; unsigned x; } c; c.h = h; return c.x;
}

// ---------------- parameter precompute ----------------
// sigmoid(sigma*(v-mu)) = 1/(1+2^(a*v+b)), a=-sigma*log2e, b=sigma*mu*log2e
// Group = 4 consecutive rows at one column j:
//   abq[g*256+j] = uint4{ h2(a_r0,a_r1), h2(b_r0,b_r1), h2(a_r2,a_r3), h2(b_r2,b_r3) }
//   wd [g*256+j] = uint2{ h2(w_r0,w_r1), h2(w_r2,w_r3) },  w = softplus(w)*erev (signed)
// num += w*s ; den += |w|*s  (abs = free v_fma_mix modifier)
__global__ __launch_bounds__(256) void prep_kernel(
    const float* __restrict__ sensory_w, const float* __restrict__ sensory_mu,
    const float* __restrict__ sensory_sigma, const float* __restrict__ sensory_erev,
    const float* __restrict__ w, const float* __restrict__ mu,
    const float* __restrict__ sigma, const float* __restrict__ erev,
    const float* __restrict__ gleak, const float* __restrict__ vleak,
    const float* __restrict__ cm,
    uint4* __restrict__ gabq, uint2* __restrict__ gwd,
    uint4* __restrict__ sabq, uint2* __restrict__ swd,
    float* __restrict__ cmt, float* __restrict__ gnum, float* __restrict__ cden)
{
    int e = blockIdx.x * 256 + threadIdx.x;
    int g = e >> 8, j = e & 255;
    if (e < 64 * 256) {                       // recurrent: 64 groups of 4 rows
        float aa[4], bb[4], ww[4];
#pragma unroll
        for (int k = 0; k < 4; ++k) {
            int idx = ((g << 2) + k) * UU + j;
            float sg = sigma[idx], m = mu[idx];
            aa[k] = -sg * LOG2E;
            bb[k] = sg * m * LOG2E;
            ww[k] = log1pf(expf(w[idx])) * erev[idx];
        }
        uint4 o;
        o.x = h2u(__floats2half2_rn(aa[0], aa[1]));
        o.y = h2u(__floats2half2_rn(bb[0], bb[1]));
        o.z = h2u(__floats2half2_rn(aa[2], aa[3]));
        o.w = h2u(__floats2half2_rn(bb[2], bb[3]));
        gabq[e] = o;
        uint2 o2;
        o2.x = h2u(__floats2half2_rn(ww[0], ww[1]));
        o2.y = h2u(__floats2half2_rn(ww[2], ww[3]));
        gwd[e] = o2;
    }
    if (e < 32 * 256) {                       // sensory: 32 groups of 4 rows
        float aa[4], bb[4], ww[4];
#pragma unroll
        for (int k = 0; k < 4; ++k) {
            int idx = ((g << 2) + k) * UU + j;
            float sg = sensory_sigma[idx], m = sensory_mu[idx];
            aa[k] = -sg * LOG2E;
            bb[k] = sg * m * LOG2E;
            ww[k] = log1pf(expf(sensory_w[idx])) * sensory_erev[idx];
        }
        uint4 o;
        o.x = h2u(__floats2half2_rn(aa[0], aa[1]));
        o.y = h2u(__floats2half2_rn(bb[0], bb[1]));
        o.z = h2u(__floats2half2_rn(aa[2], aa[3]));
        o.w = h2u(__floats2half2_rn(bb[2], bb[3]));
        sabq[e] = o;
        uint2 o2;
        o2.x = h2u(__floats2half2_rn(ww[0], ww[1]));
        o2.y = h2u(__floats2half2_rn(ww[2], ww[3]));
        swd[e] = o2;
    }
    if (e < UU) {
        float gl = log1pf(expf(gleak[e]));
        float c = log1pf(expf(cm[e])) * 6.0f;   // ODE_UNFOLDS=6, ts=1
        cmt[e] = c;
        gnum[e] = gl * vleak[e];
        cden[e] = c + gl + 1e-8f;
    }
}

// process 4 rows: packed f16 z, f16 exp/rcp, f32 mix-accumulate
__device__ __forceinline__ void proc4(uint4 qab, uint2 qw, unsigned pv01, unsigned pv23,
                                      float& num, float& den)
{
    const __half one = __ushort_as_half((unsigned short)0x3C00);
    __half2 z0 = __hfma2(u2h(qab.x), u2h(pv01), u2h(qab.y));
    __half2 z1 = __hfma2(u2h(qab.z), u2h(pv23), u2h(qab.w));
    float s0 = __half2float(hrcp(__hadd(hexp2(__low2half(z0)), one)));
    float s1 = __half2float(hrcp(__hadd(hexp2(__high2half(z0)), one)));
    float s2 = __half2float(hrcp(__hadd(hexp2(__low2half(z1)), one)));
    float s3 = __half2float(hrcp(__hadd(hexp2(__high2half(z1)), one)));
    float w0 = __half2float(__low2half(u2h(qw.x)));
    float w1 = __half2float(__high2half(u2h(qw.x)));
    float w2 = __half2float(__low2half(u2h(qw.y)));
    float w3 = __half2float(__high2half(u2h(qw.y)));
    num = fmaf(w0, s0, num); den = fmaf(fabsf(w0), s0, den);
    num = fmaf(w1, s1, num); den = fmaf(fabsf(w1), s1, den);
    num = fmaf(w2, s2, num); den = fmaf(fabsf(w2), s2, den);
    num = fmaf(w3, s3, num); den = fmaf(fabsf(w3), s3, den);
}

// pack two readlane'd f16 v values (SALU pack off the VALU pipe)
#define PKRL(VH, A, B) ((unsigned)((__builtin_amdgcn_readlane((int)(VH), (A)) & 0xFFFF) | \
                                   (__builtin_amdgcn_readlane((int)(VH), (B)) << 16)))

// ---------------- main kernel: 1 block = 1 batch element, 16 waves ----------------
// wave (qi=wv&3, qj=wv>>2): columns j = 64qj+l, rows [64qi, 64qi+64) = 16 groups,
// all streamed from L2 (params fully L2-resident; FETCH stays ~10 MB).
// v lane-distributed: lane l of qi-row waves holds v[64qi+l] (f32 + f16 bits vh).
// Bitwise fixed-point detection: once v_new==v_old for all 256 units (wave __all +
// per-qi LDS flags riding the unfold barrier, 1-unfold lag), the deterministic map
// is the identity forever within this t -> skip all remaining ODE work (EXACT).
__global__ __launch_bounds__(1024) void ltc_kernel(
    const float* __restrict__ x,
    const float* __restrict__ input_w, const float* __restrict__ input_b,
    const float* __restrict__ halt_w, const float* __restrict__ halt_b,
    const float* __restrict__ out_w, const float* __restrict__ out_b,
    const uint4* __restrict__ gabq, const uint2* __restrict__ gwd,
    const uint4* __restrict__ sabq, const uint2* __restrict__ swd,
    const float* __restrict__ cmt_g, const float* __restrict__ gnum_g,
    const float* __restrict__ cden_g,
    float* __restrict__ readout, float* __restrict__ h_state, float* __restrict__ ponder_out)
{
    const int b = blockIdx.x, tid = threadIdx.x;
    const int wv = tid >> 6, l = tid & 63;
    const int qi = wv & 3, qj = wv >> 2;
    const int j = (qj << 6) + l;
    const int u = (qi << 6) + l;

    __shared__ float2 part[2][4][UU];     // 16 KB (num,den), double-buffered
    __shared__ unsigned xin2[64];         // packed half2 xin pairs
    __shared__ float red[4];
    __shared__ __align__(16) int flg[2][4];   // per-qi convergence flags, dbuf

    const float cmtu = cmt_g[u], gnu = gnum_g[u], cdu = cden_g[u];
    const float hwu = halt_w[u], owu = out_w[u], obu = out_b[u];
    const float hb = halt_b[0];
    float2 iw2 = {0.f, 0.f}, ib2 = {0.f, 0.f};
    if (tid < 64) {
        iw2 = ((const float2*)input_w)[tid];
        ib2 = ((const float2*)input_b)[tid];
    }

    float v = 0.0f;
    int vh = 0;               // f16 bits of v, low 16
    unsigned prevb = 0;       // f32 bits of v after previous update
    float pond = 0.0f;

    for (int t = 0; t < TT; ++t) {
        // ---- input mapping: packed half2 pairs ----
        if (tid < 64) {
            float2 xv = ((const float2*)(x + ((size_t)b * TT + t) * SS))[tid];
            xin2[tid] = h2u(__floats2half2_rn(fmaf(xv.x, iw2.x, ib2.x),
                                              fmaf(xv.y, iw2.y, ib2.y)));
        }
        __syncthreads();

        // ---- sensory partials: 8 groups (rows [32qi,32qi+32)), L2-streamed ----
        {
            float num = 0.f, den = 0.f;
            const uint4* pA = sabq + ((qi << 3) << 8) + j;
            const uint2* pW = swd + ((qi << 3) << 8) + j;
            uint4 qa = pA[0]; uint2 qw = pW[0];
#pragma unroll 1
            for (int c = 0; c < 8; ++c) {
                uint4 na = qa; uint2 nw = qw;
                if (c < 7) { na = pA[(c + 1) << 8]; nw = pW[(c + 1) << 8]; }
                uint2 xp = *(const uint2*)&xin2[((qi << 3) + c) << 1];
                proc4(qa, qw, xp.x, xp.y, num, den);
                qa = na; qw = nw;
            }
            part[0][qi][j] = make_float2(num, den);
        }
        __syncthreads();
        float basen, based;
        {
            float2 s0 = part[0][0][u], s1 = part[0][1][u];
            float2 s2 = part[0][2][u], s3 = part[0][3][u];
            basen = s0.x + s1.x + s2.x + s3.x + gnu;
            based = s0.y + s1.y + s2.y + s3.y + cdu;
        }

        int pb = 1;
        float accA = 0.0f, halt_sum = 0.0f, rem = 0.0f;
        int nupd = 0;
        bool conv = false;    // bitwise fixed point reached for this t
        int predv = 0;        // last v-update was identity (this lane's unit)
        prevb = __float_as_uint(v) ^ 0x80000000u;   // force "changed" at t start

        // ---- ACT loop (uniform early exit) ----
#pragma unroll 1
        for (int n = 0; n < 10; ++n) {
            const bool convStart = conv;
            if (!conv) {
#pragma unroll 1
                for (int uu = 0; uu < 6; ++uu) {
                    float num = 0.f, den = 0.f;
                    const uint4* pA = gabq + ((qi << 4) << 8) + j;
                    const uint2* pW = gwd + ((qi << 4) << 8) + j;
                    uint4 qa = pA[0]; uint2 qw = pW[0];
#pragma unroll 1
                    for (int c = 0; c < 16; ++c) {
                        uint4 na = qa; uint2 nw = qw;
                        if (c < 15) { na = pA[(c + 1) << 8]; nw = pW[(c + 1) << 8]; }
                        unsigned p01 = PKRL(vh, 4 * c, 4 * c + 1);
                        unsigned p23 = PKRL(vh, 4 * c + 2, 4 * c + 3);
                        proc4(qa, qw, p01, p23, num, den);
                        qa = na; qw = nw;
                    }
                    part[pb][qi][j] = make_float2(num, den);
                    int af = __all(predv);
                    if (qj == 0 && l == 0) flg[pb][qi] = af;
                    __syncthreads();
                    int4 fv = *(const int4*)&flg[pb][0];
                    if (fv.x && fv.y && fv.z && fv.w) {
                        conv = true;          // map is identity from here on (exact)
                        pb ^= 1;
                        break;
                    }
                    // redundant per-wave v-update for own units
                    float2 p0 = part[pb][0][u], p1 = part[pb][1][u];
                    float2 p2 = part[pb][2][u], p3 = part[pb][3][u];
                    float tn = p0.x + p1.x + p2.x + p3.x + basen;
                    float td = p0.y + p1.y + p2.y + p3.y + based;
                    v = fmaf(cmtu, v, tn) * __builtin_amdgcn_rcpf(td);
                    unsigned nb = __float_as_uint(v);
                    predv = (nb == prevb);
                    prevb = nb;
                    vh = (int)__half_as_ushort(__float2half(v));
                    pb ^= 1;
                }
            }

            // halting p = sigmoid(v . halt_w + hb); recompute only if v may have
            // changed since the last p evaluation (convStart false)
            if (!convStart) {
                if (qj == 0) {
                    float hp = v * hwu;
                    hp += __shfl_down(hp, 32, 64);
                    hp += __shfl_down(hp, 16, 64);
                    hp += __shfl_down(hp, 8, 64);
                    hp += __shfl_down(hp, 4, 64);
                    hp += __shfl_down(hp, 2, 64);
                    hp += __shfl_down(hp, 1, 64);
                    if (l == 0) red[qi] = hp;
                }
                __syncthreads();
            }
            float dot = red[0] + red[1] + red[2] + red[3] + hb;
            float pr = __builtin_amdgcn_rcpf(1.0f + __builtin_amdgcn_exp2f(-dot * LOG2E));
            float new_sum = halt_sum + pr;
            bool halting = (n == 9) || (new_sum >= 0.99f);
            float r = 1.0f - halt_sum;
            float wgt = halting ? r : pr;
            accA = fmaf(wgt, v, accA);
            if (halting) rem += r;
            halt_sum = new_sum;
            ++nupd;
            if (halting) break;
        }

        // ---- t epilogue: new_state = accA ----
        if (qj == 0)
            readout[((size_t)b * TT + t) * UU + u] = fmaf(accA, owu, obu);
        v = accA;
        vh = (int)__half_as_ushort(__float2half(v));
        pond += (float)nupd + rem;
    }

    if (qj == 0) h_state[(size_t)b * UU + u] = v;
    if (tid == 0) atomicAdd(ponder_out, pond * (1.0f / BB));
}

// ---------------- launch ----------------
extern "C" void kernel_launch(void* const* d_in, const int* in_sizes, int n_in,
                              void* d_out, int out_size, void* d_ws, size_t ws_size,
                              hipStream_t stream)
{
    const float* x             = (const float*)d_in[0];
    const float* input_w       = (const float*)d_in[1];
    const float* input_b       = (const float*)d_in[2];
    const float* sensory_w     = (const float*)d_in[3];
    const float* sensory_mu    = (const float*)d_in[4];
    const float* sensory_sigma = (const float*)d_in[5];
    const float* sensory_erev  = (const float*)d_in[6];
    const float* w             = (const float*)d_in[7];
    const float* mu            = (const float*)d_in[8];
    const float* sigma         = (const float*)d_in[9];
    const float* erev          = (const float*)d_in[10];
    const float* gleak         = (const float*)d_in[11];
    const float* vleak         = (const float*)d_in[12];
    const float* cm            = (const float*)d_in[13];
    const float* output_w      = (const float*)d_in[14];
    const float* output_b      = (const float*)d_in[15];
    const float* halt_w        = (const float*)d_in[16];
    const float* halt_b        = (const float*)d_in[17];

    float* readout = (float*)d_out;
    float* h_state = readout + (size_t)BB * TT * UU;
    float* ponder  = h_state + (size_t)BB * UU;

    char* wsb = (char*)d_ws;
    uint4* gabq = (uint4*)wsb;  wsb += (size_t)64 * 256 * sizeof(uint4);
    uint2* gwd  = (uint2*)wsb;  wsb += (size_t)64 * 256 * sizeof(uint2);
    uint4* sabq = (uint4*)wsb;  wsb += (size_t)32 * 256 * sizeof(uint4);
    uint2* swd  = (uint2*)wsb;  wsb += (size_t)32 * 256 * sizeof(uint2);
    float* cmt  = (float*)wsb;  wsb += (size_t)UU * 4;
    float* gnum = (float*)wsb;  wsb += (size_t)UU * 4;
    float* cden = (float*)wsb;  wsb += (size_t)UU * 4;

    hipMemsetAsync(ponder, 0, sizeof(float), stream);
    prep_kernel<<<64, 256, 0, stream>>>(
        sensory_w, sensory_mu, sensory_sigma, sensory_erev,
        w, mu, sigma, erev, gleak, vleak, cm,
        gabq, gwd, sabq, swd, cmt, gnum, cden);
    ltc_kernel<<<BB, 1024, 0, stream>>>(
        x, input_w, input_b, halt_w, halt_b, output_w, output_b,
        gabq, gwd, sabq, swd, cmt, gnum, cden,
        readout, h_state, ponder);
}